// Round 9
// baseline (359.049 us; speedup 1.0000x reference)
//
#include <hip/hip_runtime.h>
#include <stdint.h>

#define B_ 16
#define K_ 2048
#define D_ 512
#define INNER_ 1024
#define M_ (B_*K_)      // 32768 rows
#define KW_ 5
#define EPS_ 1e-5f
#define NC_ 64
#define CL_ (K_/NC_)    // 32 per chunk

typedef __attribute__((ext_vector_type(8))) short short8;
typedef __attribute__((ext_vector_type(4))) float f32x4;
typedef __attribute__((ext_vector_type(8))) float f32x8;

typedef const __attribute__((address_space(1))) unsigned int* gas_u32;
typedef __attribute__((address_space(3))) unsigned int* las_u32;

static __device__ __forceinline__ float bf2f(unsigned short u) {
    unsigned int v = ((unsigned int)u) << 16;
    return __builtin_bit_cast(float, v);
}
static __device__ __forceinline__ unsigned short f2bf(float f) {
    unsigned int x = __builtin_bit_cast(unsigned int, f);
    unsigned int r = (x + 0x7FFFu + ((x >> 16) & 1u)) >> 16;
    return (unsigned short)r;
}
static __device__ __forceinline__ f32x8 cvt8(short8 v) {
    f32x8 f;
    #pragma unroll
    for (int j = 0; j < 8; ++j) f[j] = bf2f((unsigned short)v[j]);
    return f;
}

// ---------------- weight fp32 -> bf16 conversion ----------------
__global__ __launch_bounds__(256) void k_wconv(const float* __restrict__ Wa,
                                               const float* __restrict__ Wb,
                                               const float* __restrict__ Wout,
                                               unsigned short* __restrict__ Wcat,
                                               unsigned short* __restrict__ WoutB) {
    const int NW = INNER_ * D_;  // 524288
    int idx = blockIdx.x * 256 + threadIdx.x;
    if (idx < NW)            Wcat[idx]       = f2bf(Wa[idx]);
    else if (idx < 2 * NW)   Wcat[idx]       = f2bf(Wb[idx - NW]);
    else                     WoutB[idx-2*NW] = f2bf(Wout[idx - 2*NW]);
}

// ---------------- RMSNorm: one wave per row of 512 ----------------
__global__ __launch_bounds__(256) void k_rmsnorm(const float* __restrict__ x,
                                                 const float* __restrict__ w,
                                                 unsigned short* __restrict__ h) {
    int row  = blockIdx.x * 4 + (threadIdx.x >> 6);
    int lane = threadIdx.x & 63;
    const float4* xr = (const float4*)(x + (size_t)row * D_);
    float4 v0 = xr[lane];
    float4 v1 = xr[64 + lane];
    float ss = v0.x*v0.x + v0.y*v0.y + v0.z*v0.z + v0.w*v0.w
             + v1.x*v1.x + v1.y*v1.y + v1.z*v1.z + v1.w*v1.w;
    #pragma unroll
    for (int off = 32; off; off >>= 1) ss += __shfl_xor(ss, off, 64);
    float r = rsqrtf(ss * (1.0f / D_) + EPS_);
    const float4* wv = (const float4*)w;
    float4 w0 = wv[lane], w1 = wv[64 + lane];
    ushort4 o0, o1;
    o0.x = f2bf(v0.x * r * w0.x); o0.y = f2bf(v0.y * r * w0.y);
    o0.z = f2bf(v0.z * r * w0.z); o0.w = f2bf(v0.w * r * w0.w);
    o1.x = f2bf(v1.x * r * w1.x); o1.y = f2bf(v1.y * r * w1.y);
    o1.z = f2bf(v1.z * r * w1.z); o1.w = f2bf(v1.w * r * w1.w);
    ushort4* hr = (ushort4*)(h + (size_t)row * D_);
    hr[lane]      = o0;
    hr[64 + lane] = o1;
}

// ---------------- 256x256 bf16 MFMA GEMM, 8-phase counted-vmcnt schedule ----
// 8 waves (2M x 4N), per-wave 128x64 out = acc[8][4]. BK=64, 2 LDS dbuf.
// 4 phases/K-tile = (kk, m-half); per phase: {ds_read 4-8, stage 2 gloads,
// barrier, 16 MFMA (setprio), barrier}; vmcnt(2) at end of ph1 & ph4 only.
// Stage order B01,B23,A02,A13 (first-need order for next tile). Per-wave
// ledger: entering tile u outstanding = A13(u)[2]; ph1-end vmcnt(2) retires
// it (guards ph2/ph4 reads); ph4-end vmcnt(2) retires B01,B23,A02(u+1).
template<int EPI>
__global__ __launch_bounds__(512) void k_gemm256(
    const unsigned short* __restrict__ A,
    const unsigned short* __restrict__ Bw,
    void* __restrict__ Cv,
    const float* __restrict__ Xadd,
    int Kd, int Nld)
{
    __shared__ __align__(16) unsigned short lA[2][256 * 64];
    __shared__ __align__(16) unsigned short lB[2][256 * 64];
    const int tid  = threadIdx.x;
    const int w    = tid >> 6, lane = tid & 63;
    const int wr   = w >> 2,   wc   = w & 3;

    // XCD-aware bijective swizzle (nwg % 8 == 0); n fastest within chunk
    const int nwg = gridDim.x * gridDim.y;
    const int fid = blockIdx.y * gridDim.x + blockIdx.x;
    const int swz = (fid & 7) * (nwg >> 3) + (fid >> 3);
    const int m0  = (swz / gridDim.y) * 256;
    const int n0  = (swz % gridDim.y) * 256;

    // staging map: chunk j (64 rows), wave w fills rows [j*64+w*8, +8)
    const int srow = w * 8 + (lane >> 3);
    const int scol = ((lane & 7) ^ (lane >> 3)) << 3; // pre-swizzled source col
    const int NT   = Kd >> 6;

    // which = 0: B chunks {0,1}; 1: B {2,3}; 2: A {0,2}; 3: A {1,3}
    auto stagePair = [&](int t, int buf, int which) {
        const int kt = t << 6;
        if (which < 2) {
            const unsigned short* gb = Bw + (size_t)(n0 + srow) * Kd + kt + scol;
            #pragma unroll
            for (int jj = 0; jj < 2; ++jj) {
                int j = which * 2 + jj;
                __builtin_amdgcn_global_load_lds((gas_u32)(gb + (size_t)j * 64 * Kd),
                    (las_u32)(&lB[buf][(j * 64 + w * 8) * 64]), 16, 0, 0);
            }
        } else {
            const unsigned short* ga = A + (size_t)(m0 + srow) * Kd + kt + scol;
            #pragma unroll
            for (int jj = 0; jj < 2; ++jj) {
                int j = (which - 2) + jj * 2;   // {0,2} or {1,3}
                __builtin_amdgcn_global_load_lds((gas_u32)(ga + (size_t)j * 64 * Kd),
                    (las_u32)(&lA[buf][(j * 64 + w * 8) * 64]), 16, 0, 0);
            }
        }
    };

    f32x4 acc[8][4];
    #pragma unroll
    for (int m = 0; m < 8; ++m)
        #pragma unroll
        for (int n = 0; n < 4; ++n) acc[m][n] = (f32x4){0.f, 0.f, 0.f, 0.f};

    const int lrow = lane & 15;
    const int hb   = (lane >> 4) << 4;   // 16B slot within 128B row
    const int xr   = (lrow & 7) << 4;    // read-side swizzle

    // prologue: tile 0 -> buf0; retire all but A13(t0)
    stagePair(0, 0, 0); stagePair(0, 0, 1); stagePair(0, 0, 2); stagePair(0, 0, 3);
    asm volatile("s_waitcnt vmcnt(2)" ::: "memory");
    __builtin_amdgcn_s_barrier();

    for (int t = 0; t < NT; ++t) {
        const int cur = t & 1, nxt = cur ^ 1;
        const bool more = (t + 1 < NT);
        const char* pa = (const char*)lA[cur];
        const char* pb = (const char*)lB[cur];
        short8 a[4], b[4];

        // ---- phase 1: (kk0, mh0) ----
        #pragma unroll
        for (int m = 0; m < 4; ++m)
            a[m] = *(const short8*)(pa + (wr*128 + m*16 + lrow) * 128 + (hb ^ xr));
        #pragma unroll
        for (int n = 0; n < 4; ++n)
            b[n] = *(const short8*)(pb + (wc*64 + n*16 + lrow) * 128 + (hb ^ xr));
        if (more) stagePair(t + 1, nxt, 0);
        __builtin_amdgcn_s_barrier();
        __builtin_amdgcn_s_setprio(1);
        #pragma unroll
        for (int m = 0; m < 4; ++m)
            #pragma unroll
            for (int n = 0; n < 4; ++n)
                acc[m][n] = __builtin_amdgcn_mfma_f32_16x16x32_bf16(a[m], b[n], acc[m][n], 0, 0, 0);
        __builtin_amdgcn_s_setprio(0);
        if (more) asm volatile("s_waitcnt vmcnt(2)" ::: "memory");
        else      asm volatile("s_waitcnt vmcnt(0)" ::: "memory");
        __builtin_amdgcn_s_barrier();

        // ---- phase 2: (kk0, mh1) ----
        #pragma unroll
        for (int m = 0; m < 4; ++m)
            a[m] = *(const short8*)(pa + (wr*128 + 64 + m*16 + lrow) * 128 + (hb ^ xr));
        if (more) stagePair(t + 1, nxt, 1);
        __builtin_amdgcn_s_barrier();
        __builtin_amdgcn_s_setprio(1);
        #pragma unroll
        for (int m = 0; m < 4; ++m)
            #pragma unroll
            for (int n = 0; n < 4; ++n)
                acc[4+m][n] = __builtin_amdgcn_mfma_f32_16x16x32_bf16(a[m], b[n], acc[4+m][n], 0, 0, 0);
        __builtin_amdgcn_s_setprio(0);
        __builtin_amdgcn_s_barrier();

        // ---- phase 3: (kk1, mh0) ----
        #pragma unroll
        for (int m = 0; m < 4; ++m)
            a[m] = *(const short8*)(pa + (wr*128 + m*16 + lrow) * 128 + ((64 + hb) ^ xr));
        #pragma unroll
        for (int n = 0; n < 4; ++n)
            b[n] = *(const short8*)(pb + (wc*64 + n*16 + lrow) * 128 + ((64 + hb) ^ xr));
        if (more) stagePair(t + 1, nxt, 2);
        __builtin_amdgcn_s_barrier();
        __builtin_amdgcn_s_setprio(1);
        #pragma unroll
        for (int m = 0; m < 4; ++m)
            #pragma unroll
            for (int n = 0; n < 4; ++n)
                acc[m][n] = __builtin_amdgcn_mfma_f32_16x16x32_bf16(a[m], b[n], acc[m][n], 0, 0, 0);
        __builtin_amdgcn_s_setprio(0);
        __builtin_amdgcn_s_barrier();

        // ---- phase 4: (kk1, mh1) ----
        #pragma unroll
        for (int m = 0; m < 4; ++m)
            a[m] = *(const short8*)(pa + (wr*128 + 64 + m*16 + lrow) * 128 + ((64 + hb) ^ xr));
        if (more) stagePair(t + 1, nxt, 3);
        __builtin_amdgcn_s_barrier();
        __builtin_amdgcn_s_setprio(1);
        #pragma unroll
        for (int m = 0; m < 4; ++m)
            #pragma unroll
            for (int n = 0; n < 4; ++n)
                acc[4+m][n] = __builtin_amdgcn_mfma_f32_16x16x32_bf16(a[m], b[n], acc[4+m][n], 0, 0, 0);
        __builtin_amdgcn_s_setprio(0);
        if (more) asm volatile("s_waitcnt vmcnt(2)" ::: "memory");
        __builtin_amdgcn_s_barrier();
    }

    // epilogue: D layout col = lane&15, row = (lane>>4)*4 + r
    #pragma unroll
    for (int m = 0; m < 8; ++m) {
        int mrow = m0 + wr*128 + m*16 + ((lane >> 4) << 2);
        #pragma unroll
        for (int n = 0; n < 4; ++n) {
            int ncol = n0 + wc*64 + n*16 + (lane & 15);
            f32x4 v = acc[m][n];
            #pragma unroll
            for (int r = 0; r < 4; ++r) {
                size_t off = (size_t)(mrow + r) * Nld + ncol;
                if (EPI == 0) ((unsigned short*)Cv)[off] = f2bf(v[r]);
                else          ((float*)Cv)[off] = Xadd[off] + v[r];
            }
        }
    }
}

// ---------------- prefix: per (b,channel), chain chunk-end states ----------
__global__ __launch_bounds__(256) void k_prefix(const float* __restrict__ alpha,
                                                const float* __restrict__ sEnd,
                                                float* __restrict__ sPre) {
    int idx = blockIdx.x * 256 + threadIdx.x;   // 0..16383
    int b = idx >> 10, i = idx & 1023;
    float Aa = 1.f / (1.f + __expf(-alpha[i]));
    float Ap = Aa;
    #pragma unroll
    for (int t = 0; t < 5; ++t) Ap = Ap * Ap;   // Aa^32 (CL=32)
    float s = 0.f;
    for (int c = 0; c < NC_; ++c) {
        size_t off = ((size_t)(b * NC_ + c)) * INNER_ + i;
        sPre[off] = s;
        s = s * Ap + sEnd[off];
    }
}

// ---------------- conv5 + SiLU + chunked selective scan (vectorized x8) -----
template<int PASS>
__global__ __launch_bounds__(256) void k_scan(
    const unsigned short* __restrict__ ab,
    const float* __restrict__ conv_w, const float* __restrict__ conv_b,
    const float* __restrict__ alpha,  const float* __restrict__ beta,
    const float* __restrict__ gamma,  const float* __restrict__ delta,
    float* __restrict__ sEnd, const float* __restrict__ sPre,
    unsigned short* __restrict__ g)
{
    const int tid = threadIdx.x;
    const int c   = blockIdx.x * 2 + (tid >> 7);   // chunk 0..63 (wave-uniform)
    const int b   = blockIdx.y;
    const int ch  = (tid & 127) * 8;               // channel base 0..1016

    f32x8 w0, w1, w2, w3, w4, bias, Aa, bet, gam, del;
    #pragma unroll
    for (int j = 0; j < 8; ++j) {
        int i = ch + j;
        w0[j] = conv_w[i*KW_+0]; w1[j] = conv_w[i*KW_+1]; w2[j] = conv_w[i*KW_+2];
        w3[j] = conv_w[i*KW_+3]; w4[j] = conv_w[i*KW_+4];
        bias[j] = conv_b[i];
        Aa[j]  = 1.f / (1.f + __expf(-alpha[i]));
        bet[j] = beta[i];
        if (PASS == 1) { gam[j] = gamma[i]; del[j] = delta[i]; }
    }

    const int k0 = c * CL_;
    const size_t rowbase = (size_t)b * K_;

    #define LDV(k) (((unsigned)(k) < (unsigned)K_) \
        ? cvt8(*(const short8*)(ab + (rowbase + (k)) * 2048 + ch)) \
        : (f32x8){0.f,0.f,0.f,0.f,0.f,0.f,0.f,0.f})

    f32x8 am2 = LDV(k0 - 2), am1 = LDV(k0 - 1), a0v = LDV(k0), ap1 = LDV(k0 + 1);

    f32x8 s;
    if (PASS == 1) {
        s = *(const f32x8*)(sPre + ((size_t)(b * NC_ + c)) * INNER_ + ch);
    } else {
        #pragma unroll
        for (int j = 0; j < 8; ++j) s[j] = 0.f;
    }

    #pragma unroll 2
    for (int kk = 0; kk < CL_; ++kk) {
        int k = k0 + kk;
        f32x8 ap2 = LDV(k + 2);
        f32x8 v = w0*am2 + w1*am1 + w2*a0v + w3*ap1 + w4*ap2 + bias;
        f32x8 u;
        #pragma unroll
        for (int j = 0; j < 8; ++j) u[j] = v[j] / (1.f + __expf(-v[j]));
        s = Aa * s + bet * u;
        if (PASS == 1) {
            f32x8 bv = cvt8(*(const short8*)(ab + (rowbase + k) * 2048 + INNER_ + ch));
            f32x8 gv = (gam * s + del * u) * bv;
            short8 o;
            #pragma unroll
            for (int j = 0; j < 8; ++j) o[j] = (short)f2bf(gv[j]);
            *(short8*)(g + (rowbase + k) * INNER_ + ch) = o;
        }
        am2 = am1; am1 = a0v; a0v = ap1; ap1 = ap2;
    }
    if (PASS == 0)
        *(f32x8*)(sEnd + ((size_t)(b * NC_ + c)) * INNER_ + ch) = s;
    #undef LDV
}

// ---------------- launch ----------------
extern "C" void kernel_launch(void* const* d_in, const int* in_sizes, int n_in,
                              void* d_out, int out_size, void* d_ws, size_t ws_size,
                              hipStream_t stream) {
    const float* x      = (const float*)d_in[0];
    const float* norm_w = (const float*)d_in[1];
    const float* Wa     = (const float*)d_in[2];
    const float* Wb     = (const float*)d_in[3];
    const float* conv_w = (const float*)d_in[4];
    const float* conv_b = (const float*)d_in[5];
    const float* alpha  = (const float*)d_in[6];
    const float* beta   = (const float*)d_in[7];
    const float* gamma  = (const float*)d_in[8];
    const float* delta  = (const float*)d_in[9];
    const float* Wout   = (const float*)d_in[10];
    float* out = (float*)d_out;

    char* ws = (char*)d_ws;
    unsigned short* h    = (unsigned short*)ws; ws += (size_t)M_ * D_ * 2;        // 32 MB
    unsigned short* Wcat = (unsigned short*)ws; ws += (size_t)2048 * 512 * 2;     // 2 MB
    unsigned short* WoB  = (unsigned short*)ws; ws += (size_t)512 * 1024 * 2;     // 1 MB
    unsigned short* abb  = (unsigned short*)ws; ws += (size_t)M_ * 2048 * 2;      // 128 MB
    unsigned short* g    = (unsigned short*)ws; ws += (size_t)M_ * 1024 * 2;      // 64 MB
    float* sEnd          = (float*)ws;          ws += (size_t)B_ * NC_ * INNER_ * 4; // 4 MB
    float* sPre          = (float*)ws;          ws += (size_t)B_ * NC_ * INNER_ * 4; // 4 MB

    k_wconv  <<<6144, 256, 0, stream>>>(Wa, Wb, Wout, Wcat, WoB);
    k_rmsnorm<<<M_ / 4, 256, 0, stream>>>(x, norm_w, h);
    // a|b = h @ [Wa;Wb]^T : M=32768, K=512, N=2048
    k_gemm256<0><<<dim3(M_ / 256, 2048 / 256), 512, 0, stream>>>(h, Wcat, abb, nullptr, 512, 2048);
    // chunked scan: pass0 (chunk ends) -> prefix chain -> pass1 (emit g)
    k_scan<0><<<dim3(NC_ / 2, B_), 256, 0, stream>>>(abb, conv_w, conv_b, alpha, beta, gamma, delta, sEnd, nullptr, g);
    k_prefix<<<64, 256, 0, stream>>>(alpha, sEnd, sPre);
    k_scan<1><<<dim3(NC_ / 2, B_), 256, 0, stream>>>(abb, conv_w, conv_b, alpha, beta, gamma, delta, sEnd, sPre, g);
    // out = x + g @ Wout^T : M=32768, K=1024, N=512
    k_gemm256<1><<<dim3(M_ / 256, 512 / 256), 512, 0, stream>>>(g, WoB, out, x, 1024, 512);
}